// Round 6
// baseline (1171.360 us; speedup 1.0000x reference)
//
#include <hip/hip_runtime.h>
#include <hip/hip_bf16.h>
#include <math.h>

#define NTOK   288      // B*L
#define NV     3
#define NTV    864      // NV*NTOK
#define NSEL   3456     // NTV*4
#define DMODEL 512
#define NEXP   16
#define TOPK   4
#define HFF    2048
#define RESN   5000
#define MAXSEG 70

typedef short v8s __attribute__((ext_vector_type(8)));
typedef float v4f __attribute__((ext_vector_type(4)));
typedef unsigned short ushort_t;

__device__ __forceinline__ float gelu_exact(float x) {
    return 0.5f * x * (1.0f + erff(x * 0.70710678118654752f));
}
__device__ __forceinline__ unsigned f2bf1(float f) {
    unsigned u = __builtin_bit_cast(unsigned, f);
    return (u + 0x7fffu + ((u >> 16) & 1u)) >> 16;
}
__device__ __forceinline__ unsigned pack2(float a, float b) {
    return f2bf1(a) | (f2bf1(b) << 16);
}
__device__ __forceinline__ float bf2f(ushort_t u) {
    return __builtin_bit_cast(float, (unsigned)u << 16);
}
// async global->LDS, 16B per lane; lds dest must be wave-uniform base (HW adds lane*16)
__device__ __forceinline__ void gload_lds16(const ushort_t* g, ushort_t* l) {
    __builtin_amdgcn_global_load_lds(
        (const __attribute__((address_space(1))) void*)g,
        (__attribute__((address_space(3))) void*)l, 16, 0, 0);
}

// monotone grid barrier: all blocks resident by construction (grid=256, <=2 blk/CU cap).
// release: threadfence by all threads; arrive: device-scope atomicAdd; acquire: fence after.
__device__ __forceinline__ void grid_sync(unsigned* cnt, unsigned target) {
    __threadfence();
    __syncthreads();
    if (threadIdx.x == 0) {
        atomicAdd(cnt, 1u);
        while (atomicAdd(cnt, 0u) < target) __builtin_amdgcn_s_sleep(2);
    }
    __syncthreads();
    __threadfence();
}

// ---------------- transpose tile helper: [K][N] fp32 -> [N][K] bf16 ----------------
// pair-packed LDS layout T32[n][k/2] (stride 33 u32): conflict-free b32 writes/reads.
__device__ __forceinline__ void tile_transpose(
    const float* __restrict__ src_b, ushort_t* __restrict__ out_b,
    int K, int N, int k0, int n0, int tid, unsigned* T32)
{
    int r2 = tid >> 3;          // 0..31 -> source row pair (2*r2, 2*r2+1)
    int c8 = tid & 7;           // 8 cols per thread
    const float* s0 = src_b + (size_t)(k0 + 2 * r2) * N + n0 + c8 * 8;
    float4 a0 = *(const float4*)(s0);
    float4 a1 = *(const float4*)(s0 + 4);
    const float* s1 = s0 + N;
    float4 b0 = *(const float4*)(s1);
    float4 b1 = *(const float4*)(s1 + 4);
    unsigned u[8];
    u[0] = pack2(a0.x, b0.x); u[1] = pack2(a0.y, b0.y);
    u[2] = pack2(a0.z, b0.z); u[3] = pack2(a0.w, b0.w);
    u[4] = pack2(a1.x, b1.x); u[5] = pack2(a1.y, b1.y);
    u[6] = pack2(a1.z, b1.z); u[7] = pack2(a1.w, b1.w);
#pragma unroll
    for (int i = 0; i < 8; ++i) T32[(c8 * 8 + i) * 33 + r2] = u[i];
    __syncthreads();
#pragma unroll
    for (int t = 0; t < 2; ++t) {
        int idx = tid + 256 * t;
        int n = idx >> 3, cg = idx & 7;     // out row n, k-group cg (8 k)
        uint4 w;
        w.x = T32[n * 33 + cg * 4 + 0];
        w.y = T32[n * 33 + cg * 4 + 1];
        w.z = T32[n * 33 + cg * 4 + 2];
        w.w = T32[n * 33 + cg * 4 + 3];
        *(uint4*)(out_b + (size_t)(n0 + n) * K + k0 + cg * 8) = w;
    }
}

// ---------------- pipelined 64x64 tile GEMM core (2-phase, gload_lds, XOR swizzle) ----------------
__device__ __forceinline__ void tile_gemm(
    const ushort_t* __restrict__ A, int lda, int m0, int mmax,
    const ushort_t* __restrict__ Wt, int ldb, int n0,
    int kp0, int nkt, ushort_t (*As)[4096], ushort_t (*Bs)[4096],
    int tid, v4f acc[4])
{
    int wv = tid >> 6, lane = tid & 63, lm = lane & 15, lq = lane >> 4;
    int srow = lane >> 3;                  // 0..7
    int schunk = (lane & 7) ^ srow;        // pre-swizzled source chunk
    int arow0 = wv * 16 + srow, arow1 = arow0 + 8;
    int ra0 = min(m0 + arow0, mmax - 1), ra1 = min(m0 + arow1, mmax - 1);
    const ushort_t* sA0 = A + (size_t)ra0 * lda + kp0 + schunk * 8;
    const ushort_t* sA1 = A + (size_t)ra1 * lda + kp0 + schunk * 8;
    const ushort_t* sB0 = Wt + (size_t)(n0 + arow0) * ldb + kp0 + schunk * 8;
    const ushort_t* sB1 = Wt + (size_t)(n0 + arow1) * ldb + kp0 + schunk * 8;
    ushort_t* lA0[2] = { &As[0][(wv * 2 + 0) * 512], &As[1][(wv * 2 + 0) * 512] };
    ushort_t* lA1[2] = { &As[0][(wv * 2 + 1) * 512], &As[1][(wv * 2 + 1) * 512] };
    ushort_t* lB0[2] = { &Bs[0][(wv * 2 + 0) * 512], &Bs[1][(wv * 2 + 0) * 512] };
    ushort_t* lB1[2] = { &Bs[0][(wv * 2 + 1) * 512], &Bs[1][(wv * 2 + 1) * 512] };
    int r8 = lm & 7;
    int aIdx = (wv * 16 + lm) * 64 + ((lq ^ r8) << 3);
    int bIdx = lm * 64 + ((lq ^ r8) << 3);

    gload_lds16(sA0, lA0[0]); gload_lds16(sA1, lA1[0]);
    gload_lds16(sB0, lB0[0]); gload_lds16(sB1, lB1[0]);
    __syncthreads();

    for (int kt = 0; kt < nkt; ++kt) {
        int cur = kt & 1;
        if (kt < nkt - 1) {
            int ko = (kt + 1) * 64;
            gload_lds16(sA0 + ko, lA0[cur ^ 1]); gload_lds16(sA1 + ko, lA1[cur ^ 1]);
            gload_lds16(sB0 + ko, lB0[cur ^ 1]); gload_lds16(sB1 + ko, lB1[cur ^ 1]);
        }
        const ushort_t* Ab = As[cur];
        const ushort_t* Bb = Bs[cur];
        v8s a0 = *(const v8s*)&Ab[aIdx];
        v8s a1 = *(const v8s*)&Ab[aIdx ^ 32];
#pragma unroll
        for (int nt = 0; nt < 4; ++nt) {
            v8s b0 = *(const v8s*)&Bb[bIdx + nt * 1024];
            v8s b1 = *(const v8s*)&Bb[(bIdx + nt * 1024) ^ 32];
            acc[nt] = __builtin_amdgcn_mfma_f32_16x16x32_bf16(a0, b0, acc[nt], 0, 0, 0);
            acc[nt] = __builtin_amdgcn_mfma_f32_16x16x32_bf16(a1, b1, acc[nt], 0, 0, 0);
        }
        __syncthreads();
    }
}

// ---------------- front: token blocks FIRST, ew1 transpose tail; LDS union ----------------
__global__ __launch_bounds__(256) void front_kernel(
    const int* __restrict__ Z,
    const float* __restrict__ emb0, const float* __restrict__ p0w, const float* __restrict__ p0b,
    const float* __restrict__ emb1, const float* __restrict__ p1w, const float* __restrict__ p1b,
    const float* __restrict__ emb2, const float* __restrict__ p2w, const float* __restrict__ p2b,
    const float* __restrict__ keys, const float* __restrict__ router_w, const float* __restrict__ router_b,
    ushort_t* __restrict__ vbf, float* __restrict__ w4, int* __restrict__ idx4,
    const float* __restrict__ ew1, ushort_t* __restrict__ ew1t)
{
    int tid = threadIdx.x;
    __shared__ __align__(16) unsigned fsm[3104];   // 12.4 KB union
    if (blockIdx.x >= NTV) {
        // ew1: fp32 [512][2048] -> bf16 [2048][512]; 8 k-tiles x 32 n-tiles per expert
        int b = blockIdx.x - NTV;           // 0..4095
        int e = b >> 8, r = b & 255;
        tile_transpose(ew1 + (size_t)e * DMODEL * HFF,
                       ew1t + (size_t)e * HFF * DMODEL,
                       DMODEL, HFF, (r >> 5) * 64, (r & 31) * 64, tid, fsm);
        return;
    }
    int tv = blockIdx.x;
    int vi = tv / NTOK, t = tv % NTOK;
    int lane = tid & 63, wv = tid >> 6;

    const float* emb; const float* pw; const float* pb; int F;
    if (vi == 0)      { emb = emb0; pw = p0w; pb = p0b; F = 200; }
    else if (vi == 1) { emb = emb1; pw = p1w; pb = p1b; F = 132; }
    else              { emb = emb2; pw = p2w; pb = p2b; F = 112; }
    const float* rw = router_w + (size_t)vi * DMODEL * NEXP;
    const float* rb = router_b + vi * NEXP;

    float* er     = (float*)fsm;
    float* part   = (float*)(fsm + 200);
    float* vs     = (float*)(fsm + 200 + 2048);
    float* red    = (float*)(fsm + 200 + 2048 + 512);
    float* logits = (float*)(fsm + 200 + 2048 + 512 + 256);
    float* vsq_s  = (float*)(fsm + 200 + 2048 + 512 + 256 + 16);

    int z = Z[t];
    for (int f = tid; f < F; f += 256) er[f] = emb[(size_t)z * F + f];
    __syncthreads();

    int c0 = lane * 8;
    float pa[8] = {0.f, 0.f, 0.f, 0.f, 0.f, 0.f, 0.f, 0.f};
    for (int f = wv; f < F; f += 4) {
        float e = er[f];
        const float* prow = pw + (size_t)f * DMODEL + c0;
        float4 w0 = *(const float4*)(prow);
        float4 w1 = *(const float4*)(prow + 4);
        pa[0] += e * w0.x; pa[1] += e * w0.y; pa[2] += e * w0.z; pa[3] += e * w0.w;
        pa[4] += e * w1.x; pa[5] += e * w1.y; pa[6] += e * w1.z; pa[7] += e * w1.w;
    }
    *(float4*)&part[wv * DMODEL + c0]     = make_float4(pa[0], pa[1], pa[2], pa[3]);
    *(float4*)&part[wv * DMODEL + c0 + 4] = make_float4(pa[4], pa[5], pa[6], pa[7]);
    __syncthreads();

    float a0 = pb[tid]       + part[tid]       + part[DMODEL + tid]       + part[2 * DMODEL + tid]       + part[3 * DMODEL + tid];
    float a1 = pb[tid + 256] + part[tid + 256] + part[DMODEL + tid + 256] + part[2 * DMODEL + tid + 256] + part[3 * DMODEL + tid + 256];
    vs[tid] = a0; vs[tid + 256] = a1;
    vbf[(size_t)tv * DMODEL + tid]       = (ushort_t)f2bf1(a0);
    vbf[(size_t)tv * DMODEL + tid + 256] = (ushort_t)f2bf1(a1);

    red[tid] = a0 * a0 + a1 * a1;
    __syncthreads();
    for (int s = 128; s > 0; s >>= 1) { if (tid < s) red[tid] += red[tid + s]; __syncthreads(); }
    if (tid == 0) vsq_s[0] = red[0];
    __syncthreads();
    float vsq = vsq_s[0];

    for (int ei = 0; ei < 4; ++ei) {
        int e = wv * 4 + ei;
        float p = 0.0f;
        for (int d = lane; d < DMODEL; d += 64) {
            float vvv = vs[d];
            float kk = keys[e * DMODEL + d];
            p += vvv * rw[d * NEXP + e] - kk * (kk - 2.0f * vvv);
        }
        for (int off = 32; off > 0; off >>= 1) p += __shfl_down(p, off, 64);
        if (lane == 0) logits[e] = -vsq + p + rb[e];
    }
    __syncthreads();

    if (tid == 0) {
        float lv[NEXP];
        for (int e = 0; e < NEXP; ++e) lv[e] = logits[e];
        bool used[NEXP] = {false};
        int   tk[TOPK]; float tval[TOPK];
        for (int k = 0; k < TOPK; ++k) {
            int best = -1; float bv = -1e30f;
            for (int e = 0; e < NEXP; ++e)
                if (!used[e] && lv[e] > bv) { bv = lv[e]; best = e; }
            used[best] = true; tk[k] = best; tval[k] = bv;
        }
        float m = tval[0], sum = 0.0f, ww[TOPK];
        for (int k = 0; k < TOPK; ++k) { ww[k] = expf(tval[k] - m); sum += ww[k]; }
        for (int k = 0; k < TOPK; ++k) {
            w4[tv * TOPK + k] = ww[k] / sum;
            idx4[tv * TOPK + k] = tk[k];
        }
    }
}

// ---------------- route: compact rows per expert + segment list (1 block) + zero barrier ----------------
__global__ __launch_bounds__(256) void route_kernel(
    const int* __restrict__ idx4, int* __restrict__ offs,
    int* __restrict__ rows_tv, int* __restrict__ rows_s,
    int* __restrict__ seg_e, int* __restrict__ seg_r0, int* __restrict__ nseg,
    unsigned* __restrict__ gcnt)
{
    __shared__ int cnt[NEXP], cur[NEXP], offsh[NEXP + 1];
    int tid = threadIdx.x;
    if (tid == 0) gcnt[0] = 0u;
    if (tid < NEXP) cnt[tid] = 0;
    __syncthreads();
    for (int s = tid; s < NSEL; s += 256) atomicAdd(&cnt[idx4[s]], 1);
    __syncthreads();
    if (tid == 0) {
        int o = 0;
        for (int e = 0; e < NEXP; ++e) { offsh[e] = o; o += cnt[e]; }
        offsh[NEXP] = o;
        int ns = 0;
        for (int e = 0; e < NEXP; ++e)
            for (int s = offsh[e]; s < offsh[e + 1]; s += 64) {
                seg_e[ns] = e; seg_r0[ns] = s; ++ns;
            }
        nseg[0] = ns;
    }
    __syncthreads();
    if (tid < NEXP) cur[tid] = offsh[tid];
    if (tid <= NEXP) offs[tid] = offsh[tid];
    __syncthreads();
    for (int s = tid; s < NSEL; s += 256) {
        int e = idx4[s];
        int pos = atomicAdd(&cur[e], 1);
        rows_tv[pos] = s >> 2;
        rows_s[pos]  = s;
    }
}

// ---------------- MoE phase 1: 2-phase pipelined gemm + ew2 transpose tail ----------------
__global__ __launch_bounds__(256) void moe_gemm1(
    const ushort_t* __restrict__ vbf, const int* __restrict__ rows_tv,
    const int* __restrict__ offs,
    const int* __restrict__ seg_e, const int* __restrict__ seg_r0, const int* __restrict__ nseg,
    const ushort_t* __restrict__ ew1t, const float* __restrict__ eb1, ushort_t* __restrict__ h,
    const float* __restrict__ ew2, ushort_t* __restrict__ ew2t)
{
    int tid = threadIdx.x;
    __shared__ __align__(16) ushort_t As[2][4096];
    __shared__ __align__(16) ushort_t Bs[2][4096];
    if ((int)blockIdx.x >= 32) {
        int b = ((int)blockIdx.x - 32) * MAXSEG + (int)blockIdx.y;   // 0..4199
        if (b < 4096) {
            int e = b >> 8, r = b & 255;
            tile_transpose(ew2 + (size_t)e * HFF * DMODEL,
                           ew2t + (size_t)e * DMODEL * HFF,
                           HFF, DMODEL, (r >> 3) * 64, (r & 7) * 64, tid,
                           (unsigned*)&As[0][0]);
        }
        return;
    }
    if ((int)blockIdx.y >= nseg[0]) return;
    int e = seg_e[blockIdx.y], r0 = seg_r0[blockIdx.y];
    int rend = offs[e + 1];
    int n0 = blockIdx.x * 64;
    const ushort_t* Wt = ew1t + (size_t)e * HFF * DMODEL;   // [2048 n][512 k] bf16
    const float* bias = eb1 + (size_t)e * HFF;
    int wv = tid >> 6, lane = tid & 63, lm = lane & 15, lq = lane >> 4;

    v4f acc[4];
#pragma unroll
    for (int nt = 0; nt < 4; ++nt) acc[nt] = (v4f){0.f, 0.f, 0.f, 0.f};
    // A rows via rows_tv indirection: inline variant of tile_gemm
    {
        int srow = lane >> 3;
        int schunk = (lane & 7) ^ srow;
        int arow0 = wv * 16 + srow, arow1 = arow0 + 8;
        int ra0 = min(r0 + arow0, rend - 1), ra1 = min(r0 + arow1, rend - 1);
        const ushort_t* sA0 = vbf + (size_t)rows_tv[ra0] * DMODEL + schunk * 8;
        const ushort_t* sA1 = vbf + (size_t)rows_tv[ra1] * DMODEL + schunk * 8;
        const ushort_t* sB0 = Wt + (size_t)(n0 + arow0) * DMODEL + schunk * 8;
        const ushort_t* sB1 = Wt + (size_t)(n0 + arow1) * DMODEL + schunk * 8;
        ushort_t* lA0[2] = { &As[0][(wv * 2 + 0) * 512], &As[1][(wv * 2 + 0) * 512] };
        ushort_t* lA1[2] = { &As[0][(wv * 2 + 1) * 512], &As[1][(wv * 2 + 1) * 512] };
        ushort_t* lB0[2] = { &Bs[0][(wv * 2 + 0) * 512], &Bs[1][(wv * 2 + 0) * 512] };
        ushort_t* lB1[2] = { &Bs[0][(wv * 2 + 1) * 512], &Bs[1][(wv * 2 + 1) * 512] };
        int r8 = lm & 7;
        int aIdx = (wv * 16 + lm) * 64 + ((lq ^ r8) << 3);
        int bIdx = lm * 64 + ((lq ^ r8) << 3);
        gload_lds16(sA0, lA0[0]); gload_lds16(sA1, lA1[0]);
        gload_lds16(sB0, lB0[0]); gload_lds16(sB1, lB1[0]);
        __syncthreads();
        for (int kt = 0; kt < 8; ++kt) {
            int cur = kt & 1;
            if (kt < 7) {
                int ko = (kt + 1) * 64;
                gload_lds16(sA0 + ko, lA0[cur ^ 1]); gload_lds16(sA1 + ko, lA1[cur ^ 1]);
                gload_lds16(sB0 + ko, lB0[cur ^ 1]); gload_lds16(sB1 + ko, lB1[cur ^ 1]);
            }
            const ushort_t* Ab = As[cur];
            const ushort_t* Bb = Bs[cur];
            v8s a0 = *(const v8s*)&Ab[aIdx];
            v8s a1 = *(const v8s*)&Ab[aIdx ^ 32];
#pragma unroll
            for (int nt = 0; nt < 4; ++nt) {
                v8s b0 = *(const v8s*)&Bb[bIdx + nt * 1024];
                v8s b1 = *(const v8s*)&Bb[(bIdx + nt * 1024) ^ 32];
                acc[nt] = __builtin_amdgcn_mfma_f32_16x16x32_bf16(a0, b0, acc[nt], 0, 0, 0);
                acc[nt] = __builtin_amdgcn_mfma_f32_16x16x32_bf16(a1, b1, acc[nt], 0, 0, 0);
            }
            __syncthreads();
        }
    }
#pragma unroll
    for (int nt = 0; nt < 4; ++nt) {
        int col = n0 + nt * 16 + lm;
        float bv = bias[col];
#pragma unroll
        for (int i = 0; i < 4; ++i) {
            int row = r0 + wv * 16 + lq * 4 + i;
            if (row < rend) {
                float val = gelu_exact(acc[nt][i] + bv);
                h[(size_t)row * HFF + col] = (ushort_t)f2bf1(val);
            }
        }
    }
}

// ---------------- MoE phase 2: 2-phase pipelined, K-split z=2 ----------------
__global__ __launch_bounds__(256) void moe_gemm2(
    const ushort_t* __restrict__ h, const int* __restrict__ rows_s,
    const int* __restrict__ offs,
    const int* __restrict__ seg_e, const int* __restrict__ seg_r0, const int* __restrict__ nseg,
    const ushort_t* __restrict__ ew2t, const float* __restrict__ eb2, float* __restrict__ yall)
{
    if ((int)blockIdx.y >= nseg[0]) return;
    int e = seg_e[blockIdx.y], r0 = seg_r0[blockIdx.y];
    int rend = offs[e + 1];
    int n0 = blockIdx.x * 64;
    int z = blockIdx.z;
    int kp0 = z * (HFF / 2);
    const ushort_t* Wt = ew2t + (size_t)e * DMODEL * HFF;   // [512 n][2048 k] bf16
    const float* bias = eb2 + (size_t)e * DMODEL;
    float* yz = yall + (size_t)z * NSEL * DMODEL;
    int tid = threadIdx.x, wv = tid >> 6, lane = tid & 63, lm = lane & 15, lq = lane >> 4;

    __shared__ __align__(16) ushort_t As[2][4096];
    __shared__ __align__(16) ushort_t Bs[2][4096];

    int srow = lane >> 3;
    int schunk = (lane & 7) ^ srow;
    int arow0 = wv * 16 + srow, arow1 = arow0 + 8;
    int ra0 = min(r0 + arow0, rend - 1), ra1 = min(r0 + arow1, rend - 1);
    const ushort_t* sA0 = h + (size_t)ra0 * HFF + kp0 + schunk * 8;
    const ushort_t* sA1 = h + (size_t)ra1 * HFF + kp0 + schunk * 8;
    const ushort_t* sB0 = Wt + (size_t)(n0 + arow0) * HFF + kp0 + schunk * 8;
    const ushort_t* sB1 = Wt + (size_t)(n0 + arow1) * HFF + kp0 + schunk * 8;
    ushort_t* lA0[2] = { &As[0][(wv * 2 + 0) * 512], &As[1][(wv * 2 + 0) * 512] };
    ushort_t* lA1[2] = { &As[0][(wv * 2 + 1) * 512], &As[1][(wv * 2 + 1) * 512] };
    ushort_t* lB0[2] = { &Bs[0][(wv * 2 + 0) * 512], &Bs[1][(wv * 2 + 0) * 512] };
    ushort_t* lB1[2] = { &Bs[0][(wv * 2 + 1) * 512], &Bs[1][(wv * 2 + 1) * 512] };

    int r8 = lm & 7;
    int aIdx = (wv * 16 + lm) * 64 + ((lq ^ r8) << 3);
    int bIdx = lm * 64 + ((lq ^ r8) << 3);

    v4f acc[4];
#pragma unroll
    for (int nt = 0; nt < 4; ++nt) acc[nt] = (v4f){0.f, 0.f, 0.f, 0.f};

    gload_lds16(sA0, lA0[0]); gload_lds16(sA1, lA1[0]);
    gload_lds16(sB0, lB0[0]); gload_lds16(sB1, lB1[0]);
    __syncthreads();

    for (int kt = 0; kt < 16; ++kt) {
        int cur = kt & 1;
        if (kt < 15) {
            int ko = (kt + 1) * 64;
            gload_lds16(sA0 + ko, lA0[cur ^ 1]); gload_lds16(sA1 + ko, lA1[cur ^ 1]);
            gload_lds16(sB0 + ko, lB0[cur ^ 1]); gload_lds16(sB1 + ko, lB1[cur ^ 1]);
        }
        const ushort_t* Ab = As[cur];
        const ushort_t* Bb = Bs[cur];
        v8s a0 = *(const v8s*)&Ab[aIdx];
        v8s a1 = *(const v8s*)&Ab[aIdx ^ 32];
#pragma unroll
        for (int nt = 0; nt < 4; ++nt) {
            v8s b0 = *(const v8s*)&Bb[bIdx + nt * 1024];
            v8s b1 = *(const v8s*)&Bb[(bIdx + nt * 1024) ^ 32];
            acc[nt] = __builtin_amdgcn_mfma_f32_16x16x32_bf16(a0, b0, acc[nt], 0, 0, 0);
            acc[nt] = __builtin_amdgcn_mfma_f32_16x16x32_bf16(a1, b1, acc[nt], 0, 0, 0);
        }
        __syncthreads();
    }
#pragma unroll
    for (int nt = 0; nt < 4; ++nt) {
        int col = n0 + nt * 16 + lm;
        float bv = (z == 0) ? bias[col] : 0.0f;
#pragma unroll
        for (int i = 0; i < 4; ++i) {
            int row = r0 + wv * 16 + lq * 4 + i;
            if (row < rend) {
                yz[(size_t)rows_s[row] * DMODEL + col] = acc[nt][i] + bv;
            }
        }
    }
}

// ---------------- fuse: MoE gather + PE + ALL transformer weight transposes ----------------
__global__ __launch_bounds__(256) void fuse_kernel(
    const float* __restrict__ y_all, const float* __restrict__ w4,
    const float* __restrict__ frac, float* __restrict__ x, ushort_t* __restrict__ xbf,
    const float* __restrict__ qkvw, const float* __restrict__ aow,
    const float* __restrict__ fw1, const float* __restrict__ fw2,
    ushort_t* __restrict__ qkvwt, ushort_t* __restrict__ aowt,
    ushort_t* __restrict__ fw1t, ushort_t* __restrict__ fw2t)
{
    int tid = threadIdx.x;
    if (blockIdx.x >= NTOK) {
        __shared__ unsigned T32sh[64 * 33];
        int b = blockIdx.x - NTOK;          // 0..2303
        const float* src; ushort_t* dst; int K, N, nt;
        if (b < 576)       {           src = qkvw; dst = qkvwt; K = 512;  N = 1536; nt = 24; }
        else if (b < 768)  { b -= 576; src = aow;  dst = aowt;  K = 512;  N = 512;  nt = 8;  }
        else if (b < 1536) { b -= 768; src = fw1;  dst = fw1t;  K = 512;  N = 2048; nt = 32; }
        else               { b -= 1536; src = fw2; dst = fw2t;  K = 2048; N = 512;  nt = 8;  }
        int per = nt * (K / 64);
        int z = b / per, r = b % per;
        size_t boff = (size_t)z * (size_t)K * N;
        tile_transpose(src + boff, dst + boff, K, N, (r / nt) * 64, (r % nt) * 64, tid, T32sh);
        return;
    }
    int t = blockIdx.x;
    __shared__ float wsh[12];
    __shared__ int idxsh[2];
    if (tid < 12) {
        int vi = tid >> 2, kk = tid & 3;
        wsh[tid] = w4[((size_t)vi * NTOK + t) * TOPK + kk];
    }
    if (tid == 0) {
        double r = (double)frac[t];
        double rl = fmax(r, 1.0 / RESN);
        int il = (int)rint(rl * RESN) - 1;
        idxsh[0] = min(max(il, 0), RESN - 1);
        double lg = log2(r);
        double rg = 0.0025 * lg * lg;
        rg = fmin(rg, 1.0);
        rg = fmax(rg, 1.0 / RESN);
        int ig = (int)rint(rg * RESN) - 1;
        idxsh[1] = min(max(ig, 0), RESN - 1);
    }
    __syncthreads();
    for (int d = tid; d < DMODEL; d += 256) {
        float acc = 0.0f;
        for (int c = 0; c < 12; ++c) {
            int vi = c >> 2, kk = c & 3;
            size_t s = ((size_t)vi * NTOK + t) * TOPK + kk;
            float y = y_all[s * DMODEL + d] + y_all[(size_t)NSEL * DMODEL + s * DMODEL + d];
            acc += wsh[c] * y;
        }
        int cc  = (d < 256) ? d : d - 256;
        int idx = (d < 256) ? idxsh[0] : idxsh[1];
        double arg = (double)idx / pow(50.0, 2.0 * (double)cc / 256.0);
        double pe = (cc & 1) ? cos(arg) : sin(arg);
        float val = acc + (float)pe;
        x[(size_t)t * DMODEL + d] = val;
        xbf[(size_t)t * DMODEL + d] = (ushort_t)f2bf1(val);
    }
}

// ---------------- persistent transformer tail: 3 layers x 5 stages, one launch ----------------
// grid = 256 blocks (1/CU; LDS 65KB -> 2/CU capacity, so all blocks resident -> barrier safe)
__global__ __launch_bounds__(256) void tail_kernel(
    float* __restrict__ xbuf, ushort_t* __restrict__ xbf,
    const ushort_t* __restrict__ qkvwt, const float* __restrict__ qkv_b,
    ushort_t* __restrict__ qkvb,
    const ushort_t* __restrict__ aowt, const float* __restrict__ aob,
    const float* __restrict__ ln1g, const float* __restrict__ ln1b,
    const ushort_t* __restrict__ fw1t, const float* __restrict__ fb1,
    ushort_t* __restrict__ f1b,
    const ushort_t* __restrict__ fw2t, const float* __restrict__ fb2,
    float* __restrict__ tmp,
    const float* __restrict__ ln2g, const float* __restrict__ ln2b,
    float* __restrict__ out, const float* __restrict__ frac,
    unsigned* __restrict__ gcnt)
{
    __shared__ __align__(16) char smem[65344];
    int tid = threadIdx.x, bid = blockIdx.x;
    int wv = tid >> 6, lane = tid & 63, lm = lane & 15, lq = lane >> 4;
    unsigned bar = 0;
    ushort_t (*As)[4096] = (ushort_t (*)[4096])smem;
    ushort_t (*Bs)[4096] = (ushort_t (*)[4096])(smem + 16384);

    for (int layer = 0; layer < 3; ++layer) {
        // ---- S1: qkv GEMM, 120 jobs (24 n-tiles x 5 m-tiles) ----
        if (bid < 120) {
            int m0 = (bid / 24) * 64, n0 = (bid % 24) * 64;
            const ushort_t* Wq = qkvwt + (size_t)layer * 1536 * 512;
            const float* bq = qkv_b + layer * 1536;
            v4f acc[4];
#pragma unroll
            for (int nt = 0; nt < 4; ++nt) acc[nt] = (v4f){0.f, 0.f, 0.f, 0.f};
            tile_gemm(xbf, 512, m0, NTOK, Wq, 512, n0, 0, 8, As, Bs, tid, acc);
#pragma unroll
            for (int nt = 0; nt < 4; ++nt) {
                int col = n0 + nt * 16 + lm;
                float bv = bq[col];
#pragma unroll
                for (int i = 0; i < 4; ++i) {
                    int row = m0 + wv * 16 + lq * 4 + i;
                    if (row < NTOK)
                        qkvb[(size_t)row * 1536 + col] = (ushort_t)f2bf1(acc[nt][i] + bv);
                }
            }
        }
        bar++; grid_sync(gcnt, bar * 256u);

        // ---- S2: attention + oproj + residual + ln1, 32 jobs ----
        if (bid < 32) {
            ushort_t* qkvs = (ushort_t*)smem;                 // [9][1536]
            ushort_t* osh  = (ushort_t*)(smem + 27648);       // [16][520]
            float*    sc   = (float*)(smem + 44288);          // [8][9][9]
            float*    res  = (float*)(smem + 46880);          // [9][512]
            const ushort_t* Wot = aowt + (size_t)layer * 512 * 512;
            const float* bo = aob + layer * 512;
            const float* g  = ln1g + layer * 512;
            const float* bb = ln1b + layer * 512;
            int t0 = bid * 9;

            for (int idx = tid; idx < 9 * 192; idx += 256) {
                int r = idx / 192, c = (idx % 192) * 8;
                *(uint4*)&qkvs[r * 1536 + c] = *(const uint4*)(qkvb + (size_t)(t0 + r) * 1536 + c);
            }
            for (int idx = tid; idx < 16 * 65; idx += 256) {
                *(uint4*)&osh[(idx / 65) * 520 + (idx % 65) * 8] = (uint4){0, 0, 0, 0};
            }
            __syncthreads();
            for (int idx = tid; idx < 648; idx += 256) {
                int hh = idx / 81, ij = idx % 81, i = ij / 9, j = ij % 9;
                const ushort_t* qr = &qkvs[i * 1536 + hh * 64];
                const ushort_t* kr = &qkvs[j * 1536 + 512 + hh * 64];
                float s = 0.0f;
                for (int d = 0; d < 64; ++d) s += bf2f(qr[d]) * bf2f(kr[d]);
                sc[(hh * 9 + i) * 9 + j] = s * 0.125f;
            }
            __syncthreads();
            if (tid < 72) {
                int hh = tid / 9, i = tid % 9;
                float m = -1e30f;
                for (int j = 0; j < 9; ++j) m = fmaxf(m, sc[(hh * 9 + i) * 9 + j]);
                float sum = 0.0f, e[9];
                for (int j = 0; j < 9; ++j) { e[j] = expf(sc[(hh * 9 + i) * 9 + j] - m); sum += e[j]; }
                for (int j = 0; j < 9; ++j) sc[(hh * 9 + i) * 9 + j] = e[j] / sum;
            }
            __syncthreads();
            for (int idx = tid; idx < 4608; idx += 256) {
                int hh = idx / 576, r = idx % 576, i = r / 64, d = r % 64;
                float a2 = 0.0f;
                for (int j = 0; j < 9; ++j)
                    a2 += sc[(hh * 9 + i) * 9 + j] * bf2f(qkvs[j * 1536 + 1024 + hh * 64 + d]);
                osh[i * 520 + hh * 64 + d] = (ushort_t)f2bf1(a2);
            }
            __syncthreads();

            v4f acc[8];
#pragma unroll
            for (int nt = 0; nt < 8; ++nt) acc[nt] = (v4f){0.f, 0.f, 0.f, 0.f};
            int n0w = wv * 128;
            for (int ks = 0; ks < 512; ks += 32) {
                v8s a = *(const v8s*)&osh[lm * 520 + ks + lq * 8];
#pragma unroll
                for (int nt = 0; nt < 8; ++nt) {
                    v8s b = *(const v8s*)(Wot + (size_t)(n0w + nt * 16 + lm) * 512 + ks + lq * 8);
                    acc[nt] = __builtin_amdgcn_mfma_f32_16x16x32_bf16(a, b, acc[nt], 0, 0, 0);
                }
            }
#pragma unroll
            for (int nt = 0; nt < 8; ++nt) {
                int col = n0w + nt * 16 + lm;
                float bv = bo[col];
#pragma unroll
                for (int i = 0; i < 4; ++i) {
                    int row = lq * 4 + i;
                    if (row < 9) res[row * 512 + col] = acc[nt][i] + bv;
                }
            }
            __syncthreads();

            for (int r = wv; r < 9; r += 4) {
                int t = t0 + r;
                size_t base = (size_t)t * DMODEL;
                int c0 = lane * 8;
                float vals[8];
                float4 x0 = *(const float4*)(xbuf + base + c0);
                float4 x1 = *(const float4*)(xbuf + base + c0 + 4);
                vals[0] = x0.x + res[r * 512 + c0 + 0]; vals[1] = x0.y + res[r * 512 + c0 + 1];
                vals[2] = x0.z + res[r * 512 + c0 + 2]; vals[3] = x0.w + res[r * 512 + c0 + 3];
                vals[4] = x1.x + res[r * 512 + c0 + 4]; vals[5] = x1.y + res[r * 512 + c0 + 5];
                vals[6] = x1.z + res[r * 512 + c0 + 6]; vals[7] = x1.w + res[r * 512 + c0 + 7];
                float s = 0.f;
#pragma unroll
                for (int i = 0; i < 8; ++i) s += vals[i];
                for (int off = 1; off < 64; off <<= 1) s += __shfl_xor(s, off, 64);
                float mean = s * (1.0f / DMODEL);
                float vvv = 0.f;
#pragma unroll
                for (int i = 0; i < 8; ++i) { vals[i] -= mean; vvv += vals[i] * vals[i]; }
                for (int off = 1; off < 64; off <<= 1) vvv += __shfl_xor(vvv, off, 64);
                float rstd = rsqrtf(vvv * (1.0f / DMODEL) + 1e-5f);
                float4 g0 = *(const float4*)(g + c0), g1 = *(const float4*)(g + c0 + 4);
                float4 b0 = *(const float4*)(bb + c0), b1 = *(const float4*)(bb + c0 + 4);
                float gs[8] = {g0.x,g0.y,g0.z,g0.w,g1.x,g1.y,g1.z,g1.w};
                float bs[8] = {b0.x,b0.y,b0.z,b0.w,b1.x,b1.y,b1.z,b1.w};
                float o[8]; uint4 pk;
#pragma unroll
                for (int i = 0; i < 8; ++i) o[i] = vals[i] * rstd * gs[i] + bs[i];
                pk.x = pack2(o[0], o[1]); pk.y = pack2(o[2], o[3]);
                pk.z = pack2(o[4], o[5]); pk.w = pack2(o[6], o[7]);
                *(float4*)(xbuf + base + c0)     = make_float4(o[0], o[1], o[2], o[3]);
                *(float4*)(xbuf + base + c0 + 4) = make_float4(o[4], o[5], o[6], o[7]);
                *(uint4*)(xbf + base + c0) = pk;
            }
        }
        bar++; grid_sync(gcnt, bar * 256u);

        // ---- S3: ffn1, 160 jobs (32 n-tiles x 5 m-tiles) ----
        if (bid < 160) {
            int m0 = (bid / 32) * 64, n0 = (bid % 32) * 64;
            const ushort_t* W1 = fw1t + (size_t)layer * 2048 * 512;
            const float* b1 = fb1 + layer * 2048;
            v4f acc[4];
#pragma unroll
            for (int nt = 0; nt < 4; ++nt) acc[nt] = (v4f){0.f, 0.f, 0.f, 0.f};
            tile_gemm(xbf, 512, m0, NTOK, W1, 512, n0, 0, 8, As, Bs, tid, acc);
#pragma unroll
            for (int nt = 0; nt < 4; ++nt) {
                int col = n0 + nt * 16 + lm;
                float bv = b1[col];
#pragma unroll
                for (int i = 0; i < 4; ++i) {
                    int row = m0 + wv * 16 + lq * 4 + i;
                    if (row < NTOK)
                        f1b[(size_t)row * 2048 + col] = (ushort_t)f2bf1(fmaxf(acc[nt][i] + bv, 0.f));
                }
            }
        }
        bar++; grid_sync(gcnt, bar * 256u);

        // ---- S4: ffn2, 160 jobs (8 n x 5 m x 4 z) ----
        if (bid < 160) {
            int z = bid / 40, rest = bid % 40;
            int m0 = (rest / 8) * 64, n0 = (rest % 8) * 64;
            const ushort_t* W2 = fw2t + (size_t)layer * 512 * 2048;
            const float* b2 = fb2 + layer * 512;
            v4f acc[4];
#pragma unroll
            for (int nt = 0; nt < 4; ++nt) acc[nt] = (v4f){0.f, 0.f, 0.f, 0.f};
            tile_gemm(f1b, 2048, m0, NTOK, W2, 2048, n0, z * 512, 8, As, Bs, tid, acc);
            float* tz = tmp + (size_t)z * NTOK * DMODEL;
#pragma unroll
            for (int nt = 0; nt < 4; ++nt) {
                int col = n0 + nt * 16 + lm;
                float bv = (z == 0) ? b2[col] : 0.0f;
#pragma unroll
                for (int i = 0; i < 4; ++i) {
                    int row = m0 + wv * 16 + lq * 4 + i;
                    if (row < NTOK)
                        tz[(size_t)row * 512 + col] = acc[nt][i] + bv;
                }
            }
        }
        bar++; grid_sync(gcnt, bar * 256u);

        // ---- S5: ln2 (+ final scale), 72 jobs ----
        if (bid < 72) {
            const float* g  = ln2g + layer * 512;
            const float* bb = ln2b + layer * 512;
            int t = bid * 4 + wv;
            size_t base = (size_t)t * DMODEL;
            int c0 = lane * 8;
            float vals[8];
            *(float4*)(vals)     = *(const float4*)(xbuf + base + c0);
            *(float4*)(vals + 4) = *(const float4*)(xbuf + base + c0 + 4);
            for (int z = 0; z < 4; ++z) {
                const float* tz = tmp + (size_t)z * NTOK * DMODEL + base + c0;
                float4 a4 = *(const float4*)tz, b4 = *(const float4*)(tz + 4);
                vals[0] += a4.x; vals[1] += a4.y; vals[2] += a4.z; vals[3] += a4.w;
                vals[4] += b4.x; vals[5] += b4.y; vals[6] += b4.z; vals[7] += b4.w;
            }
            float s = 0.f;
#pragma unroll
            for (int i = 0; i < 8; ++i) s += vals[i];
            for (int off = 1; off < 64; off <<= 1) s += __shfl_xor(s, off, 64);
            float mean = s * (1.0f / DMODEL);
            float vvv = 0.f;
#pragma unroll
            for (int i = 0; i < 8; ++i) { vals[i] -= mean; vvv += vals[i] * vals[i]; }
            for (int off = 1; off < 64; off <<= 1) vvv += __shfl_xor(vvv, off, 64);
            float rstd = rsqrtf(vvv * (1.0f / DMODEL) + 1e-5f);
            float4 g0 = *(const float4*)(g + c0), g1 = *(const float4*)(g + c0 + 4);
            float4 b0 = *(const float4*)(bb + c0), b1 = *(const float4*)(bb + c0 + 4);
            float gs[8] = {g0.x,g0.y,g0.z,g0.w,g1.x,g1.y,g1.z,g1.w};
            float bs[8] = {b0.x,b0.y,b0.z,b0.w,b1.x,b1.y,b1.z,b1.w};
            float o[8]; uint4 pk;
#pragma unroll
            for (int i = 0; i < 8; ++i) o[i] = vals[i] * rstd * gs[i] + bs[i];
            pk.x = pack2(o[0], o[1]); pk.y = pack2(o[2], o[3]);
            pk.z = pack2(o[4], o[5]); pk.w = pack2(o[6], o[7]);
            *(float4*)(xbuf + base + c0)     = make_float4(o[0], o[1], o[2], o[3]);
            *(float4*)(xbuf + base + c0 + 4) = make_float4(o[4], o[5], o[6], o[7]);
            *(uint4*)(xbf + base + c0) = pk;
            if (layer == 2) {
                float fr = frac[t];
                *(float4*)(out + base + c0)     = make_float4(o[0]*fr, o[1]*fr, o[2]*fr, o[3]*fr);
                *(float4*)(out + base + c0 + 4) = make_float4(o[4]*fr, o[5]*fr, o[6]*fr, o[7]*fr);
            }
        }
        if (layer < 2) { bar++; grid_sync(gcnt, bar * 256u); }
    }
}

extern "C" void kernel_launch(void* const* d_in, const int* in_sizes, int n_in,
                              void* d_out, int out_size, void* d_ws, size_t ws_size,
                              hipStream_t stream) {
    const int*   Z      = (const int*)d_in[0];
    const float* frac   = (const float*)d_in[1];
    const float* emb0   = (const float*)d_in[2];
    const float* p0w    = (const float*)d_in[3];
    const float* p0b    = (const float*)d_in[4];
    const float* emb1   = (const float*)d_in[5];
    const float* p1w    = (const float*)d_in[6];
    const float* p1b    = (const float*)d_in[7];
    const float* emb2   = (const float*)d_in[8];
    const float* p2w    = (const float*)d_in[9];
    const float* p2b    = (const float*)d_in[10];
    const float* keys   = (const float*)d_in[11];
    const float* rw     = (const float*)d_in[12];
    const float* rb     = (const float*)d_in[13];
    const float* ew1    = (const float*)d_in[14];
    const float* eb1    = (const float*)d_in[15];
    const float* ew2    = (const float*)d_in[16];
    const float* eb2    = (const float*)d_in[17];
    const float* qkv_w  = (const float*)d_in[18];
    const float* qkv_b  = (const float*)d_in[19];
    const float* aow    = (const float*)d_in[20];
    const float* aob    = (const float*)d_in[21];
    const float* ln1g   = (const float*)d_in[22];
    const float* ln1b   = (const float*)d_in[23];
    const float* ln2g   = (const float*)d_in[24];
    const float* ln2b   = (const float*)d_in[25];
    const float* fw1    = (const float*)d_in[26];
    const float* fb1    = (const float*)d_in[27];
    const float* fw2    = (const float*)d_in[28];
    const float* fb2    = (const float*)d_in[29];
    float* out = (float*)d_out;

    // workspace layout (~121 MB, no aliasing)
    char* p = (char*)d_ws;
    ushort_t* vbf  = (ushort_t*)p;      p += 864 * 512 * 2;
    ushort_t* h    = (ushort_t*)p;      p += 3456 * 2048 * 2;
    float* yall    = (float*)p;         p += 2 * 3456 * 512 * 4;
    ushort_t* qkvwt= (ushort_t*)p;      p += 3 * 1536 * 512 * 2;
    ushort_t* aowt = (ushort_t*)p;      p += 3 * 512 * 512 * 2;
    ushort_t* fw1t = (ushort_t*)p;      p += 3 * 2048 * 512 * 2;
    ushort_t* fw2t = (ushort_t*)p;      p += 3 * 512 * 2048 * 2;
    ushort_t* ew1t = (ushort_t*)p;      p += (size_t)NEXP * 2048 * 512 * 2;
    ushort_t* ew2t = (ushort_t*)p;      p += (size_t)NEXP * 512 * 2048 * 2;
    float* xbuf = (float*)p;            p += 288 * 512 * 4;
    ushort_t* xbf = (ushort_t*)p;       p += 288 * 512 * 2;
    ushort_t* qkvb = (ushort_t*)p;      p += 288 * 1536 * 2;
    float* tmp  = (float*)p;            p += 4 * 288 * 512 * 4;
    ushort_t* f1b = (ushort_t*)p;       p += 288 * 2048 * 2;
    float* w4   = (float*)p;            p += 3456 * 4;
    int* idx4   = (int*)p;              p += 3456 * 4;
    int* offs   = (int*)p;              p += 256;
    int* rows_tv= (int*)p;              p += 3456 * 4;
    int* rows_s = (int*)p;              p += 3456 * 4;
    int* seg_e  = (int*)p;              p += 128 * 4;
    int* seg_r0 = (int*)p;              p += 128 * 4;
    int* nseg   = (int*)p;              p += 256;
    unsigned* gcnt = (unsigned*)p;      p += 256;

    // front: 864 token blocks FIRST + 4096 ew1-transpose tail (overlap within launch)
    front_kernel<<<dim3(NTV + 4096), dim3(256), 0, stream>>>(
        Z, emb0, p0w, p0b, emb1, p1w, p1b, emb2, p2w, p2b,
        keys, rw, rb, vbf, w4, idx4, ew1, ew1t);
    route_kernel<<<dim3(1), dim3(256), 0, stream>>>(idx4, offs, rows_tv, rows_s,
                                                    seg_e, seg_r0, nseg, gcnt);
    moe_gemm1<<<dim3(32 + 60, MAXSEG), dim3(256), 0, stream>>>(
        vbf, rows_tv, offs, seg_e, seg_r0, nseg, ew1t, eb1, h, ew2, ew2t);
    moe_gemm2<<<dim3(DMODEL / 64, MAXSEG, 2), dim3(256), 0, stream>>>(
        h, rows_s, offs, seg_e, seg_r0, nseg, ew2t, eb2, yall);
    // fuse: 288 token blocks + 2304 transpose blocks (qkvw/aow/fw1/fw2)
    fuse_kernel<<<dim3(NTOK + 2304), dim3(256), 0, stream>>>(
        yall, w4, frac, xbuf, xbf, qkv_w, aow, fw1, fw2, qkvwt, aowt, fw1t, fw2t);
    // persistent transformer tail: one launch, 14 grid barriers
    tail_kernel<<<dim3(256), dim3(256), 0, stream>>>(
        xbuf, xbf, qkvwt, qkv_b, qkvb, aowt, aob, ln1g, ln1b,
        fw1t, fb1, f1b, fw2t, fb2, tmp, ln2g, ln2b, out, frac, gcnt);
}

// Round 8
// 517.581 us; speedup vs baseline: 2.2631x; 2.2631x over previous
//
#include <hip/hip_runtime.h>
#include <hip/hip_bf16.h>
#include <math.h>

#define NTOK   288      // B*L
#define NV     3
#define NTV    864      // NV*NTOK
#define NSEL   3456     // NTV*4
#define DMODEL 512
#define NEXP   16
#define TOPK   4
#define HFF    2048
#define RESN   5000
#define MAXSEG 70

typedef short v8s __attribute__((ext_vector_type(8)));
typedef float v4f __attribute__((ext_vector_type(4)));
typedef unsigned short ushort_t;

__device__ __forceinline__ float gelu_exact(float x) {
    return 0.5f * x * (1.0f + erff(x * 0.70710678118654752f));
}
__device__ __forceinline__ unsigned f2bf1(float f) {
    unsigned u = __builtin_bit_cast(unsigned, f);
    return (u + 0x7fffu + ((u >> 16) & 1u)) >> 16;
}
__device__ __forceinline__ unsigned pack2(float a, float b) {
    return f2bf1(a) | (f2bf1(b) << 16);
}
__device__ __forceinline__ float bf2f(ushort_t u) {
    return __builtin_bit_cast(float, (unsigned)u << 16);
}
// async global->LDS, 16B per lane; lds dest must be wave-uniform base (HW adds lane*16)
__device__ __forceinline__ void gload_lds16(const ushort_t* g, ushort_t* l) {
    __builtin_amdgcn_global_load_lds(
        (const __attribute__((address_space(1))) void*)g,
        (__attribute__((address_space(3))) void*)l, 16, 0, 0);
}

// ---------------- transpose tile helper: [K][N] fp32 -> [N][K] bf16 ----------------
// pair-packed LDS layout T32[n][k/2] (stride 33 u32): conflict-free b32 writes/reads,
// output u32 = (k,k+1) bf16 pair written directly as uint4 (128B/row coalesced).
// T32 must point to >= 64*33 u32 (8448 B) of LDS.
__device__ __forceinline__ void tile_transpose(
    const float* __restrict__ src_b, ushort_t* __restrict__ out_b,
    int K, int N, int k0, int n0, int tid, unsigned* T32)
{
    int r2 = tid >> 3;          // 0..31 -> source row pair (2*r2, 2*r2+1)
    int c8 = tid & 7;           // 8 cols per thread
    const float* s0 = src_b + (size_t)(k0 + 2 * r2) * N + n0 + c8 * 8;
    float4 a0 = *(const float4*)(s0);
    float4 a1 = *(const float4*)(s0 + 4);
    const float* s1 = s0 + N;
    float4 b0 = *(const float4*)(s1);
    float4 b1 = *(const float4*)(s1 + 4);
    unsigned u[8];
    u[0] = pack2(a0.x, b0.x); u[1] = pack2(a0.y, b0.y);
    u[2] = pack2(a0.z, b0.z); u[3] = pack2(a0.w, b0.w);
    u[4] = pack2(a1.x, b1.x); u[5] = pack2(a1.y, b1.y);
    u[6] = pack2(a1.z, b1.z); u[7] = pack2(a1.w, b1.w);
#pragma unroll
    for (int i = 0; i < 8; ++i) T32[(c8 * 8 + i) * 33 + r2] = u[i];
    __syncthreads();
#pragma unroll
    for (int t = 0; t < 2; ++t) {
        int idx = tid + 256 * t;
        int n = idx >> 3, cg = idx & 7;     // out row n, k-group cg (8 k)
        uint4 w;
        w.x = T32[n * 33 + cg * 4 + 0];
        w.y = T32[n * 33 + cg * 4 + 1];
        w.z = T32[n * 33 + cg * 4 + 2];
        w.w = T32[n * 33 + cg * 4 + 3];
        *(uint4*)(out_b + (size_t)(n0 + n) * K + k0 + cg * 8) = w;
    }
}

// ---------------- pipelined 64x64 tile GEMM core (2-phase, gload_lds, XOR swizzle) ----------------
// A row-major [*][lda] bf16, rows clamped to mmax-1; Wt row-major [N][ldb] bf16.
__device__ __forceinline__ void tile_gemm(
    const ushort_t* __restrict__ A, int lda, int m0, int mmax,
    const ushort_t* __restrict__ Wt, int ldb, int n0,
    int kp0, int nkt, ushort_t (*As)[4096], ushort_t (*Bs)[4096],
    int tid, v4f acc[4])
{
    int wv = tid >> 6, lane = tid & 63, lm = lane & 15, lq = lane >> 4;
    int srow = lane >> 3;                  // 0..7
    int schunk = (lane & 7) ^ srow;        // pre-swizzled source chunk
    int arow0 = wv * 16 + srow, arow1 = arow0 + 8;
    int ra0 = min(m0 + arow0, mmax - 1), ra1 = min(m0 + arow1, mmax - 1);
    const ushort_t* sA0 = A + (size_t)ra0 * lda + kp0 + schunk * 8;
    const ushort_t* sA1 = A + (size_t)ra1 * lda + kp0 + schunk * 8;
    const ushort_t* sB0 = Wt + (size_t)(n0 + arow0) * ldb + kp0 + schunk * 8;
    const ushort_t* sB1 = Wt + (size_t)(n0 + arow1) * ldb + kp0 + schunk * 8;
    ushort_t* lA0[2] = { &As[0][(wv * 2 + 0) * 512], &As[1][(wv * 2 + 0) * 512] };
    ushort_t* lA1[2] = { &As[0][(wv * 2 + 1) * 512], &As[1][(wv * 2 + 1) * 512] };
    ushort_t* lB0[2] = { &Bs[0][(wv * 2 + 0) * 512], &Bs[1][(wv * 2 + 0) * 512] };
    ushort_t* lB1[2] = { &Bs[0][(wv * 2 + 1) * 512], &Bs[1][(wv * 2 + 1) * 512] };
    int r8 = lm & 7;
    int aIdx = (wv * 16 + lm) * 64 + ((lq ^ r8) << 3);
    int bIdx = lm * 64 + ((lq ^ r8) << 3);

    gload_lds16(sA0, lA0[0]); gload_lds16(sA1, lA1[0]);
    gload_lds16(sB0, lB0[0]); gload_lds16(sB1, lB1[0]);
    __syncthreads();

    for (int kt = 0; kt < nkt; ++kt) {
        int cur = kt & 1;
        if (kt < nkt - 1) {
            int ko = (kt + 1) * 64;
            gload_lds16(sA0 + ko, lA0[cur ^ 1]); gload_lds16(sA1 + ko, lA1[cur ^ 1]);
            gload_lds16(sB0 + ko, lB0[cur ^ 1]); gload_lds16(sB1 + ko, lB1[cur ^ 1]);
        }
        const ushort_t* Ab = As[cur];
        const ushort_t* Bb = Bs[cur];
        v8s a0 = *(const v8s*)&Ab[aIdx];
        v8s a1 = *(const v8s*)&Ab[aIdx ^ 32];
#pragma unroll
        for (int nt = 0; nt < 4; ++nt) {
            v8s b0 = *(const v8s*)&Bb[bIdx + nt * 1024];
            v8s b1 = *(const v8s*)&Bb[(bIdx + nt * 1024) ^ 32];
            acc[nt] = __builtin_amdgcn_mfma_f32_16x16x32_bf16(a0, b0, acc[nt], 0, 0, 0);
            acc[nt] = __builtin_amdgcn_mfma_f32_16x16x32_bf16(a1, b1, acc[nt], 0, 0, 0);
        }
        __syncthreads();
    }
}

// ---------------- front: token blocks FIRST + ALL MoE weight transposes (8192 tail) ----------------
__global__ __launch_bounds__(256) void front_kernel(
    const int* __restrict__ Z,
    const float* __restrict__ emb0, const float* __restrict__ p0w, const float* __restrict__ p0b,
    const float* __restrict__ emb1, const float* __restrict__ p1w, const float* __restrict__ p1b,
    const float* __restrict__ emb2, const float* __restrict__ p2w, const float* __restrict__ p2b,
    const float* __restrict__ keys, const float* __restrict__ router_w, const float* __restrict__ router_b,
    ushort_t* __restrict__ vbf, float* __restrict__ w4, int* __restrict__ idx4,
    const float* __restrict__ ew1, const float* __restrict__ ew2,
    ushort_t* __restrict__ ew1t, ushort_t* __restrict__ ew2t)
{
    int tid = threadIdx.x;
    __shared__ __align__(16) unsigned fsm[3104];   // 12.4 KB union (token path + transpose T32)
    if (blockIdx.x >= NTV) {
        int b = blockIdx.x - NTV;           // 0..8191
        if (b < 4096) {
            int e = b >> 8, r = b & 255;    // ew1: [512][2048] -> [2048][512]
            tile_transpose(ew1 + (size_t)e * DMODEL * HFF,
                           ew1t + (size_t)e * HFF * DMODEL,
                           DMODEL, HFF, (r >> 5) * 64, (r & 31) * 64, tid, fsm);
        } else {
            b -= 4096;
            int e = b >> 8, r = b & 255;    // ew2: [2048][512] -> [512][2048]
            tile_transpose(ew2 + (size_t)e * HFF * DMODEL,
                           ew2t + (size_t)e * DMODEL * HFF,
                           HFF, DMODEL, (r >> 3) * 64, (r & 7) * 64, tid, fsm);
        }
        return;
    }
    int tv = blockIdx.x;
    int vi = tv / NTOK, t = tv % NTOK;
    int lane = tid & 63, wv = tid >> 6;

    const float* emb; const float* pw; const float* pb; int F;
    if (vi == 0)      { emb = emb0; pw = p0w; pb = p0b; F = 200; }
    else if (vi == 1) { emb = emb1; pw = p1w; pb = p1b; F = 132; }
    else              { emb = emb2; pw = p2w; pb = p2b; F = 112; }
    const float* rw = router_w + (size_t)vi * DMODEL * NEXP;
    const float* rb = router_b + vi * NEXP;

    // LDS union layout (u32 offsets): er[200] | part[4*512] | vs[512] | red[256] | logits[16] | vsq[1]
    float* er     = (float*)fsm;
    float* part   = (float*)(fsm + 200);
    float* vs     = (float*)(fsm + 200 + 2048);
    float* red    = (float*)(fsm + 200 + 2048 + 512);
    float* logits = (float*)(fsm + 200 + 2048 + 512 + 256);
    float* vsq_s  = (float*)(fsm + 200 + 2048 + 512 + 256 + 16);

    int z = Z[t];
    for (int f = tid; f < F; f += 256) er[f] = emb[(size_t)z * F + f];
    __syncthreads();

    int c0 = lane * 8;
    float pa[8] = {0.f, 0.f, 0.f, 0.f, 0.f, 0.f, 0.f, 0.f};
    for (int f = wv; f < F; f += 4) {
        float e = er[f];
        const float* prow = pw + (size_t)f * DMODEL + c0;
        float4 w0 = *(const float4*)(prow);
        float4 w1 = *(const float4*)(prow + 4);
        pa[0] += e * w0.x; pa[1] += e * w0.y; pa[2] += e * w0.z; pa[3] += e * w0.w;
        pa[4] += e * w1.x; pa[5] += e * w1.y; pa[6] += e * w1.z; pa[7] += e * w1.w;
    }
    *(float4*)&part[wv * DMODEL + c0]     = make_float4(pa[0], pa[1], pa[2], pa[3]);
    *(float4*)&part[wv * DMODEL + c0 + 4] = make_float4(pa[4], pa[5], pa[6], pa[7]);
    __syncthreads();

    float a0 = pb[tid]       + part[tid]       + part[DMODEL + tid]       + part[2 * DMODEL + tid]       + part[3 * DMODEL + tid];
    float a1 = pb[tid + 256] + part[tid + 256] + part[DMODEL + tid + 256] + part[2 * DMODEL + tid + 256] + part[3 * DMODEL + tid + 256];
    vs[tid] = a0; vs[tid + 256] = a1;
    vbf[(size_t)tv * DMODEL + tid]       = (ushort_t)f2bf1(a0);
    vbf[(size_t)tv * DMODEL + tid + 256] = (ushort_t)f2bf1(a1);

    red[tid] = a0 * a0 + a1 * a1;
    __syncthreads();
    for (int s = 128; s > 0; s >>= 1) { if (tid < s) red[tid] += red[tid + s]; __syncthreads(); }
    if (tid == 0) vsq_s[0] = red[0];
    __syncthreads();
    float vsq = vsq_s[0];

    for (int ei = 0; ei < 4; ++ei) {
        int e = wv * 4 + ei;
        float p = 0.0f;
        for (int d = lane; d < DMODEL; d += 64) {
            float vvv = vs[d];
            float kk = keys[e * DMODEL + d];
            p += vvv * rw[d * NEXP + e] - kk * (kk - 2.0f * vvv);
        }
        for (int off = 32; off > 0; off >>= 1) p += __shfl_down(p, off, 64);
        if (lane == 0) logits[e] = -vsq + p + rb[e];
    }
    __syncthreads();

    if (tid == 0) {
        float lv[NEXP];
        for (int e = 0; e < NEXP; ++e) lv[e] = logits[e];
        bool used[NEXP] = {false};
        int   tk[TOPK]; float tval[TOPK];
        for (int k = 0; k < TOPK; ++k) {
            int best = -1; float bv = -1e30f;
            for (int e = 0; e < NEXP; ++e)
                if (!used[e] && lv[e] > bv) { bv = lv[e]; best = e; }
            used[best] = true; tk[k] = best; tval[k] = bv;
        }
        float m = tval[0], sum = 0.0f, ww[TOPK];
        for (int k = 0; k < TOPK; ++k) { ww[k] = expf(tval[k] - m); sum += ww[k]; }
        for (int k = 0; k < TOPK; ++k) {
            w4[tv * TOPK + k] = ww[k] / sum;
            idx4[tv * TOPK + k] = tk[k];
        }
    }
}

// ---------------- route: compact rows per expert + 64-row segment list (1 block) ----------------
__global__ __launch_bounds__(256) void route_kernel(
    const int* __restrict__ idx4, int* __restrict__ offs,
    int* __restrict__ rows_tv, int* __restrict__ rows_s,
    int* __restrict__ seg_e, int* __restrict__ seg_r0, int* __restrict__ nseg)
{
    __shared__ int cnt[NEXP], cur[NEXP], offsh[NEXP + 1];
    int tid = threadIdx.x;
    if (tid < NEXP) cnt[tid] = 0;
    __syncthreads();
    for (int s = tid; s < NSEL; s += 256) atomicAdd(&cnt[idx4[s]], 1);
    __syncthreads();
    if (tid == 0) {
        int o = 0;
        for (int e = 0; e < NEXP; ++e) { offsh[e] = o; o += cnt[e]; }
        offsh[NEXP] = o;
        int ns = 0;
        for (int e = 0; e < NEXP; ++e)
            for (int s = offsh[e]; s < offsh[e + 1]; s += 64) {
                seg_e[ns] = e; seg_r0[ns] = s; ++ns;
            }
        nseg[0] = ns;
    }
    __syncthreads();
    if (tid < NEXP) cur[tid] = offsh[tid];
    if (tid <= NEXP) offs[tid] = offsh[tid];
    __syncthreads();
    for (int s = tid; s < NSEL; s += 256) {
        int e = idx4[s];
        int pos = atomicAdd(&cur[e], 1);
        rows_tv[pos] = s >> 2;
        rows_s[pos]  = s;
    }
}

// ---------------- MoE phase 1: 2-phase pipelined, gload_lds staging, swizzled LDS ----------------
// grid (2048/64, MAXSEG)
__global__ __launch_bounds__(256) void moe_gemm1(
    const ushort_t* __restrict__ vbf, const int* __restrict__ rows_tv,
    const int* __restrict__ offs,
    const int* __restrict__ seg_e, const int* __restrict__ seg_r0, const int* __restrict__ nseg,
    const ushort_t* __restrict__ ew1t, const float* __restrict__ eb1, ushort_t* __restrict__ h)
{
    if ((int)blockIdx.y >= nseg[0]) return;
    int e = seg_e[blockIdx.y], r0 = seg_r0[blockIdx.y];
    int rend = offs[e + 1];
    int n0 = blockIdx.x * 64;
    const ushort_t* Wt = ew1t + (size_t)e * HFF * DMODEL;   // [2048 n][512 k] bf16
    const float* bias = eb1 + (size_t)e * HFF;
    int tid = threadIdx.x, wv = tid >> 6, lane = tid & 63, lm = lane & 15, lq = lane >> 4;

    __shared__ __align__(16) ushort_t As[2][4096];
    __shared__ __align__(16) ushort_t Bs[2][4096];

    int srow = lane >> 3;
    int schunk = (lane & 7) ^ srow;
    int arow0 = wv * 16 + srow, arow1 = arow0 + 8;
    int ra0 = min(r0 + arow0, rend - 1), ra1 = min(r0 + arow1, rend - 1);
    const ushort_t* sA0 = vbf + (size_t)rows_tv[ra0] * DMODEL + schunk * 8;
    const ushort_t* sA1 = vbf + (size_t)rows_tv[ra1] * DMODEL + schunk * 8;
    const ushort_t* sB0 = Wt + (size_t)(n0 + arow0) * DMODEL + schunk * 8;
    const ushort_t* sB1 = Wt + (size_t)(n0 + arow1) * DMODEL + schunk * 8;
    ushort_t* lA0[2] = { &As[0][(wv * 2 + 0) * 512], &As[1][(wv * 2 + 0) * 512] };
    ushort_t* lA1[2] = { &As[0][(wv * 2 + 1) * 512], &As[1][(wv * 2 + 1) * 512] };
    ushort_t* lB0[2] = { &Bs[0][(wv * 2 + 0) * 512], &Bs[1][(wv * 2 + 0) * 512] };
    ushort_t* lB1[2] = { &Bs[0][(wv * 2 + 1) * 512], &Bs[1][(wv * 2 + 1) * 512] };

    int r8 = lm & 7;
    int aIdx = (wv * 16 + lm) * 64 + ((lq ^ r8) << 3);
    int bIdx = lm * 64 + ((lq ^ r8) << 3);

    v4f acc[4];
#pragma unroll
    for (int nt = 0; nt < 4; ++nt) acc[nt] = (v4f){0.f, 0.f, 0.f, 0.f};

    gload_lds16(sA0, lA0[0]); gload_lds16(sA1, lA1[0]);
    gload_lds16(sB0, lB0[0]); gload_lds16(sB1, lB1[0]);
    __syncthreads();

    for (int kt = 0; kt < 8; ++kt) {
        int cur = kt & 1;
        if (kt < 7) {
            int ko = (kt + 1) * 64;
            gload_lds16(sA0 + ko, lA0[cur ^ 1]); gload_lds16(sA1 + ko, lA1[cur ^ 1]);
            gload_lds16(sB0 + ko, lB0[cur ^ 1]); gload_lds16(sB1 + ko, lB1[cur ^ 1]);
        }
        const ushort_t* Ab = As[cur];
        const ushort_t* Bb = Bs[cur];
        v8s a0 = *(const v8s*)&Ab[aIdx];
        v8s a1 = *(const v8s*)&Ab[aIdx ^ 32];
#pragma unroll
        for (int nt = 0; nt < 4; ++nt) {
            v8s b0 = *(const v8s*)&Bb[bIdx + nt * 1024];
            v8s b1 = *(const v8s*)&Bb[(bIdx + nt * 1024) ^ 32];
            acc[nt] = __builtin_amdgcn_mfma_f32_16x16x32_bf16(a0, b0, acc[nt], 0, 0, 0);
            acc[nt] = __builtin_amdgcn_mfma_f32_16x16x32_bf16(a1, b1, acc[nt], 0, 0, 0);
        }
        __syncthreads();
    }
#pragma unroll
    for (int nt = 0; nt < 4; ++nt) {
        int col = n0 + nt * 16 + lm;
        float bv = bias[col];
#pragma unroll
        for (int i = 0; i < 4; ++i) {
            int row = r0 + wv * 16 + lq * 4 + i;
            if (row < rend) {
                float val = gelu_exact(acc[nt][i] + bv);
                h[(size_t)row * HFF + col] = (ushort_t)f2bf1(val);
            }
        }
    }
}

// ---------------- MoE phase 2: 2-phase pipelined, K-split z=2 ----------------
// grid (512/64, MAXSEG, 2)
__global__ __launch_bounds__(256) void moe_gemm2(
    const ushort_t* __restrict__ h, const int* __restrict__ rows_s,
    const int* __restrict__ offs,
    const int* __restrict__ seg_e, const int* __restrict__ seg_r0, const int* __restrict__ nseg,
    const ushort_t* __restrict__ ew2t, const float* __restrict__ eb2, float* __restrict__ yall)
{
    if ((int)blockIdx.y >= nseg[0]) return;
    int e = seg_e[blockIdx.y], r0 = seg_r0[blockIdx.y];
    int rend = offs[e + 1];
    int n0 = blockIdx.x * 64;
    int z = blockIdx.z;
    int kp0 = z * (HFF / 2);
    const ushort_t* Wt = ew2t + (size_t)e * DMODEL * HFF;   // [512 n][2048 k] bf16
    const float* bias = eb2 + (size_t)e * DMODEL;
    float* yz = yall + (size_t)z * NSEL * DMODEL;
    int tid = threadIdx.x, wv = tid >> 6, lane = tid & 63, lm = lane & 15, lq = lane >> 4;

    __shared__ __align__(16) ushort_t As[2][4096];
    __shared__ __align__(16) ushort_t Bs[2][4096];

    int srow = lane >> 3;
    int schunk = (lane & 7) ^ srow;
    int arow0 = wv * 16 + srow, arow1 = arow0 + 8;
    int ra0 = min(r0 + arow0, rend - 1), ra1 = min(r0 + arow1, rend - 1);
    const ushort_t* sA0 = h + (size_t)ra0 * HFF + kp0 + schunk * 8;
    const ushort_t* sA1 = h + (size_t)ra1 * HFF + kp0 + schunk * 8;
    const ushort_t* sB0 = Wt + (size_t)(n0 + arow0) * HFF + kp0 + schunk * 8;
    const ushort_t* sB1 = Wt + (size_t)(n0 + arow1) * HFF + kp0 + schunk * 8;
    ushort_t* lA0[2] = { &As[0][(wv * 2 + 0) * 512], &As[1][(wv * 2 + 0) * 512] };
    ushort_t* lA1[2] = { &As[0][(wv * 2 + 1) * 512], &As[1][(wv * 2 + 1) * 512] };
    ushort_t* lB0[2] = { &Bs[0][(wv * 2 + 0) * 512], &Bs[1][(wv * 2 + 0) * 512] };
    ushort_t* lB1[2] = { &Bs[0][(wv * 2 + 1) * 512], &Bs[1][(wv * 2 + 1) * 512] };

    int r8 = lm & 7;
    int aIdx = (wv * 16 + lm) * 64 + ((lq ^ r8) << 3);
    int bIdx = lm * 64 + ((lq ^ r8) << 3);

    v4f acc[4];
#pragma unroll
    for (int nt = 0; nt < 4; ++nt) acc[nt] = (v4f){0.f, 0.f, 0.f, 0.f};

    gload_lds16(sA0, lA0[0]); gload_lds16(sA1, lA1[0]);
    gload_lds16(sB0, lB0[0]); gload_lds16(sB1, lB1[0]);
    __syncthreads();

    for (int kt = 0; kt < 16; ++kt) {
        int cur = kt & 1;
        if (kt < 15) {
            int ko = (kt + 1) * 64;
            gload_lds16(sA0 + ko, lA0[cur ^ 1]); gload_lds16(sA1 + ko, lA1[cur ^ 1]);
            gload_lds16(sB0 + ko, lB0[cur ^ 1]); gload_lds16(sB1 + ko, lB1[cur ^ 1]);
        }
        const ushort_t* Ab = As[cur];
        const ushort_t* Bb = Bs[cur];
        v8s a0 = *(const v8s*)&Ab[aIdx];
        v8s a1 = *(const v8s*)&Ab[aIdx ^ 32];
#pragma unroll
        for (int nt = 0; nt < 4; ++nt) {
            v8s b0 = *(const v8s*)&Bb[bIdx + nt * 1024];
            v8s b1 = *(const v8s*)&Bb[(bIdx + nt * 1024) ^ 32];
            acc[nt] = __builtin_amdgcn_mfma_f32_16x16x32_bf16(a0, b0, acc[nt], 0, 0, 0);
            acc[nt] = __builtin_amdgcn_mfma_f32_16x16x32_bf16(a1, b1, acc[nt], 0, 0, 0);
        }
        __syncthreads();
    }
#pragma unroll
    for (int nt = 0; nt < 4; ++nt) {
        int col = n0 + nt * 16 + lm;
        float bv = (z == 0) ? bias[col] : 0.0f;
#pragma unroll
        for (int i = 0; i < 4; ++i) {
            int row = r0 + wv * 16 + lq * 4 + i;
            if (row < rend) {
                yz[(size_t)rows_s[row] * DMODEL + col] = acc[nt][i] + bv;
            }
        }
    }
}

// ---------------- fuse: MoE gather + PE  (+ qkv/aow/fw1 transposes tail) ----------------
__global__ __launch_bounds__(256) void fuse_kernel(
    const float* __restrict__ y_all, const float* __restrict__ w4,
    const float* __restrict__ frac, float* __restrict__ x, ushort_t* __restrict__ xbf,
    const float* __restrict__ qkvw, const float* __restrict__ aow, const float* __restrict__ fw1,
    ushort_t* __restrict__ qkvwt, ushort_t* __restrict__ aowt, ushort_t* __restrict__ fw1t)
{
    int tid = threadIdx.x;
    if (blockIdx.x >= NTOK) {
        __shared__ __align__(16) unsigned T32sh[64 * 33];
        int b = blockIdx.x - NTOK;          // 0..1535
        const float* src; ushort_t* dst; int K, N, nt;
        if (b < 576)      {          src = qkvw; dst = qkvwt; K = 512; N = 1536; nt = 24; }
        else if (b < 768) { b -= 576; src = aow;  dst = aowt;  K = 512; N = 512;  nt = 8;  }
        else              { b -= 768; src = fw1;  dst = fw1t;  K = 512; N = 2048; nt = 32; }
        int per = nt * (K / 64);
        int z = b / per, r = b % per;
        size_t boff = (size_t)z * (size_t)K * N;
        tile_transpose(src + boff, dst + boff, K, N, (r / nt) * 64, (r % nt) * 64, tid, T32sh);
        return;
    }
    int t = blockIdx.x;
    __shared__ float wsh[12];
    __shared__ int idxsh[2];
    if (tid < 12) {
        int vi = tid >> 2, kk = tid & 3;
        wsh[tid] = w4[((size_t)vi * NTOK + t) * TOPK + kk];
    }
    if (tid == 0) {
        double r = (double)frac[t];
        double rl = fmax(r, 1.0 / RESN);
        int il = (int)rint(rl * RESN) - 1;
        idxsh[0] = min(max(il, 0), RESN - 1);
        double lg = log2(r);
        double rg = 0.0025 * lg * lg;
        rg = fmin(rg, 1.0);
        rg = fmax(rg, 1.0 / RESN);
        int ig = (int)rint(rg * RESN) - 1;
        idxsh[1] = min(max(ig, 0), RESN - 1);
    }
    __syncthreads();
    for (int d = tid; d < DMODEL; d += 256) {
        float acc = 0.0f;
        for (int c = 0; c < 12; ++c) {
            int vi = c >> 2, kk = c & 3;
            size_t s = ((size_t)vi * NTOK + t) * TOPK + kk;
            float y = y_all[s * DMODEL + d] + y_all[(size_t)NSEL * DMODEL + s * DMODEL + d];
            acc += wsh[c] * y;
        }
        int cc  = (d < 256) ? d : d - 256;
        int idx = (d < 256) ? idxsh[0] : idxsh[1];
        double arg = (double)idx / pow(50.0, 2.0 * (double)cc / 256.0);
        double pe = (cc & 1) ? cos(arg) : sin(arg);
        float val = acc + (float)pe;
        x[(size_t)t * DMODEL + d] = val;
        xbf[(size_t)t * DMODEL + d] = (ushort_t)f2bf1(val);
    }
}

// ---------------- qkv: pipelined tile gemm (grid (24[,+154],5)) + fw2 transpose tail L0 ----------------
__global__ __launch_bounds__(256) void qkv_kernel(
    const ushort_t* __restrict__ xbf, const ushort_t* __restrict__ Wq,
    const float* __restrict__ bq, ushort_t* __restrict__ qkvb,
    const float* __restrict__ fw2, ushort_t* __restrict__ fw2t)
{
    int tid = threadIdx.x;
    __shared__ __align__(16) ushort_t As[2][4096];
    __shared__ __align__(16) ushort_t Bs[2][4096];
    if ((int)blockIdx.x >= 24) {
        int b = ((int)blockIdx.x - 24) * 5 + (int)blockIdx.y;  // 0..769
        if (b < 768) {
            int z = b / 256, r = b % 256;
            int n0 = (r % 8) * 64, k0 = (r / 8) * 64;
            size_t boff = (size_t)z * 2048 * 512;
            tile_transpose(fw2 + boff, fw2t + boff, 2048, 512, k0, n0, tid,
                           (unsigned*)&As[0][0]);
        }
        return;
    }
    int m0 = blockIdx.y * 64, n0 = blockIdx.x * 64;
    v4f acc[4];
#pragma unroll
    for (int nt = 0; nt < 4; ++nt) acc[nt] = (v4f){0.f, 0.f, 0.f, 0.f};
    tile_gemm(xbf, 512, m0, NTOK, Wq, 512, n0, 0, 8, As, Bs, tid, acc);
    int wv = tid >> 6, lane = tid & 63, lm = lane & 15, lq = lane >> 4;
#pragma unroll
    for (int nt = 0; nt < 4; ++nt) {
        int col = n0 + nt * 16 + lm;
        float bv = bq[col];
#pragma unroll
        for (int i = 0; i < 4; ++i) {
            int row = m0 + wv * 16 + lq * 4 + i;
            if (row < NTOK)
                qkvb[(size_t)row * 1536 + col] = (ushort_t)f2bf1(acc[nt][i] + bv);
        }
    }
}

// ---------------- attention + oproj + residual + ln1: one block per batch ----------------
__global__ __launch_bounds__(256) void attn_block(
    const ushort_t* __restrict__ qkvb, const ushort_t* __restrict__ Wot,
    const float* __restrict__ bo, float* __restrict__ xbuf, ushort_t* __restrict__ xbf,
    const float* __restrict__ g, const float* __restrict__ bb)
{
    int bbk = blockIdx.x, t0 = bbk * 9;
    int tid = threadIdx.x, wv = tid >> 6, lane = tid & 63, lm = lane & 15, lq = lane >> 4;

    __shared__ ushort_t qkvs[9][1536];
    __shared__ ushort_t osh[16][520];
    __shared__ float sc[8][9][9];
    __shared__ float res[9][512];

    for (int idx = tid; idx < 9 * 192; idx += 256) {
        int r = idx / 192, c = (idx % 192) * 8;
        *(uint4*)&qkvs[r][c] = *(const uint4*)(qkvb + (size_t)(t0 + r) * 1536 + c);
    }
    for (int idx = tid; idx < 16 * 65; idx += 256) {
        *(uint4*)&osh[idx / 65][(idx % 65) * 8] = (uint4){0, 0, 0, 0};
    }
    __syncthreads();

    for (int idx = tid; idx < 648; idx += 256) {
        int hh = idx / 81, ij = idx % 81, i = ij / 9, j = ij % 9;
        const ushort_t* qr = &qkvs[i][hh * 64];
        const ushort_t* kr = &qkvs[j][512 + hh * 64];
        float s = 0.0f;
        for (int d = 0; d < 64; ++d) s += bf2f(qr[d]) * bf2f(kr[d]);
        sc[hh][i][j] = s * 0.125f;
    }
    __syncthreads();
    if (tid < 72) {
        int hh = tid / 9, i = tid % 9;
        float m = -1e30f;
        for (int j = 0; j < 9; ++j) m = fmaxf(m, sc[hh][i][j]);
        float sum = 0.0f, e[9];
        for (int j = 0; j < 9; ++j) { e[j] = expf(sc[hh][i][j] - m); sum += e[j]; }
        for (int j = 0; j < 9; ++j) sc[hh][i][j] = e[j] / sum;
    }
    __syncthreads();
    for (int idx = tid; idx < 4608; idx += 256) {
        int hh = idx / 576, r = idx % 576, i = r / 64, d = r % 64;
        float acc = 0.0f;
        for (int j = 0; j < 9; ++j) acc += sc[hh][i][j] * bf2f(qkvs[j][1024 + hh * 64 + d]);
        osh[i][hh * 64 + d] = (ushort_t)f2bf1(acc);
    }
    __syncthreads();

    v4f acc[8];
#pragma unroll
    for (int nt = 0; nt < 8; ++nt) acc[nt] = (v4f){0.f, 0.f, 0.f, 0.f};
    int n0w = wv * 128;
    for (int ks = 0; ks < 512; ks += 32) {
        v8s a = *(const v8s*)&osh[lm][ks + lq * 8];
#pragma unroll
        for (int nt = 0; nt < 8; ++nt) {
            v8s b = *(const v8s*)(Wot + (size_t)(n0w + nt * 16 + lm) * 512 + ks + lq * 8);
            acc[nt] = __builtin_amdgcn_mfma_f32_16x16x32_bf16(a, b, acc[nt], 0, 0, 0);
        }
    }
#pragma unroll
    for (int nt = 0; nt < 8; ++nt) {
        int col = n0w + nt * 16 + lm;
        float bv = bo[col];
#pragma unroll
        for (int i = 0; i < 4; ++i) {
            int row = lq * 4 + i;
            if (row < 9) res[row][col] = acc[nt][i] + bv;
        }
    }
    __syncthreads();

    for (int r = wv; r < 9; r += 4) {
        int t = t0 + r;
        size_t base = (size_t)t * DMODEL;
        int c0 = lane * 8;
        float vals[8];
        float4 x0 = *(const float4*)(xbuf + base + c0);
        float4 x1 = *(const float4*)(xbuf + base + c0 + 4);
        vals[0] = x0.x + res[r][c0 + 0]; vals[1] = x0.y + res[r][c0 + 1];
        vals[2] = x0.z + res[r][c0 + 2]; vals[3] = x0.w + res[r][c0 + 3];
        vals[4] = x1.x + res[r][c0 + 4]; vals[5] = x1.y + res[r][c0 + 5];
        vals[6] = x1.z + res[r][c0 + 6]; vals[7] = x1.w + res[r][c0 + 7];
        float s = 0.f;
#pragma unroll
        for (int i = 0; i < 8; ++i) s += vals[i];
        for (int off = 1; off < 64; off <<= 1) s += __shfl_xor(s, off, 64);
        float mean = s * (1.0f / DMODEL);
        float vvv = 0.f;
#pragma unroll
        for (int i = 0; i < 8; ++i) { vals[i] -= mean; vvv += vals[i] * vals[i]; }
        for (int off = 1; off < 64; off <<= 1) vvv += __shfl_xor(vvv, off, 64);
        float rstd = rsqrtf(vvv * (1.0f / DMODEL) + 1e-5f);
        float4 g0 = *(const float4*)(g + c0), g1 = *(const float4*)(g + c0 + 4);
        float4 b0 = *(const float4*)(bb + c0), b1 = *(const float4*)(bb + c0 + 4);
        float gs[8] = {g0.x,g0.y,g0.z,g0.w,g1.x,g1.y,g1.z,g1.w};
        float bs[8] = {b0.x,b0.y,b0.z,b0.w,b1.x,b1.y,b1.z,b1.w};
        float o[8]; uint4 pk;
#pragma unroll
        for (int i = 0; i < 8; ++i) o[i] = vals[i] * rstd * gs[i] + bs[i];
        pk.x = pack2(o[0], o[1]); pk.y = pack2(o[2], o[3]);
        pk.z = pack2(o[4], o[5]); pk.w = pack2(o[6], o[7]);
        *(float4*)(xbuf + base + c0)     = make_float4(o[0], o[1], o[2], o[3]);
        *(float4*)(xbuf + base + c0 + 4) = make_float4(o[4], o[5], o[6], o[7]);
        *(uint4*)(xbf + base + c0) = pk;
    }
}

// ---------------- ffn1: pipelined tile gemm, grid (32,5) ----------------
__global__ __launch_bounds__(256) void ffn1_kernel(
    const ushort_t* __restrict__ xbf, const ushort_t* __restrict__ W1,
    const float* __restrict__ b1, ushort_t* __restrict__ f1b)
{
    int tid = threadIdx.x;
    __shared__ __align__(16) ushort_t As[2][4096];
    __shared__ __align__(16) ushort_t Bs[2][4096];
    int m0 = blockIdx.y * 64, n0 = blockIdx.x * 64;
    v4f acc[4];
#pragma unroll
    for (int nt = 0; nt < 4; ++nt) acc[nt] = (v4f){0.f, 0.f, 0.f, 0.f};
    tile_gemm(xbf, 512, m0, NTOK, W1, 512, n0, 0, 8, As, Bs, tid, acc);
    int wv = tid >> 6, lane = tid & 63, lm = lane & 15, lq = lane >> 4;
#pragma unroll
    for (int nt = 0; nt < 4; ++nt) {
        int col = n0 + nt * 16 + lm;
        float bv = b1[col];
#pragma unroll
        for (int i = 0; i < 4; ++i) {
            int row = m0 + wv * 16 + lq * 4 + i;
            if (row < NTOK)
                f1b[(size_t)row * 2048 + col] = (ushort_t)f2bf1(fmaxf(acc[nt][i] + bv, 0.f));
        }
    }
}

// ---------------- ffn2: pipelined tile gemm, K-split z=4, grid (8,5,4) ----------------
__global__ __launch_bounds__(256) void ffn2_kernel(
    const ushort_t* __restrict__ f1b, const ushort_t* __restrict__ W2,
    const float* __restrict__ b2, float* __restrict__ tmp)
{
    int tid = threadIdx.x;
    __shared__ __align__(16) ushort_t As[2][4096];
    __shared__ __align__(16) ushort_t Bs[2][4096];
    int m0 = blockIdx.y * 64, n0 = blockIdx.x * 64;
    int z = blockIdx.z;
    v4f acc[4];
#pragma unroll
    for (int nt = 0; nt < 4; ++nt) acc[nt] = (v4f){0.f, 0.f, 0.f, 0.f};
    tile_gemm(f1b, 2048, m0, NTOK, W2, 2048, n0, z * 512, 8, As, Bs, tid, acc);
    int wv = tid >> 6, lane = tid & 63, lm = lane & 15, lq = lane >> 4;
    float* tz = tmp + (size_t)z * NTOK * DMODEL;
#pragma unroll
    for (int nt = 0; nt < 4; ++nt) {
        int col = n0 + nt * 16 + lm;
        float bv = (z == 0) ? b2[col] : 0.0f;
#pragma unroll
        for (int i = 0; i < 4; ++i) {
            int row = m0 + wv * 16 + lq * 4 + i;
            if (row < NTOK)
                tz[(size_t)row * 512 + col] = acc[nt][i] + bv;
        }
    }
}

// ---------------- ln2: residual(4 partials) + LN (+final scale) ----------------
__global__ __launch_bounds__(256) void ln2_kernel(
    float* __restrict__ xbuf, ushort_t* __restrict__ xbf,
    const float* __restrict__ tmp,
    const float* __restrict__ g, const float* __restrict__ bb,
    float* __restrict__ out, const float* __restrict__ frac)
{
    int tid = threadIdx.x, wv = tid >> 6, lane = tid & 63;
    int t = blockIdx.x * 4 + wv;
    size_t base = (size_t)t * DMODEL;
    int c0 = lane * 8;
    float vals[8];
    *(float4*)(vals)     = *(const float4*)(xbuf + base + c0);
    *(float4*)(vals + 4) = *(const float4*)(xbuf + base + c0 + 4);
    for (int z = 0; z < 4; ++z) {
        const float* tz = tmp + (size_t)z * NTOK * DMODEL + base + c0;
        float4 a4 = *(const float4*)tz, b4 = *(const float4*)(tz + 4);
        vals[0] += a4.x; vals[1] += a4.y; vals[2] += a4.z; vals[3] += a4.w;
        vals[4] += b4.x; vals[5] += b4.y; vals[6] += b4.z; vals[7] += b4.w;
    }
    float s = 0.f;
#pragma unroll
    for (int i = 0; i < 8; ++i) s += vals[i];
    for (int off = 1; off < 64; off <<= 1) s += __shfl_xor(s, off, 64);
    float mean = s * (1.0f / DMODEL);
    float vvv = 0.f;
#pragma unroll
    for (int i = 0; i < 8; ++i) { vals[i] -= mean; vvv += vals[i] * vals[i]; }
    for (int off = 1; off < 64; off <<= 1) vvv += __shfl_xor(vvv, off, 64);
    float rstd = rsqrtf(vvv * (1.0f / DMODEL) + 1e-5f);
    float4 g0 = *(const float4*)(g + c0), g1 = *(const float4*)(g + c0 + 4);
    float4 b0 = *(const float4*)(bb + c0), b1 = *(const float4*)(bb + c0 + 4);
    float gs[8] = {g0.x,g0.y,g0.z,g0.w,g1.x,g1.y,g1.z,g1.w};
    float bs[8] = {b0.x,b0.y,b0.z,b0.w,b1.x,b1.y,b1.z,b1.w};
    float o[8]; uint4 pk;
#pragma unroll
    for (int i = 0; i < 8; ++i) o[i] = vals[i] * rstd * gs[i] + bs[i];
    pk.x = pack2(o[0], o[1]); pk.y = pack2(o[2], o[3]);
    pk.z = pack2(o[4], o[5]); pk.w = pack2(o[6], o[7]);
    *(float4*)(xbuf + base + c0)     = make_float4(o[0], o[1], o[2], o[3]);
    *(float4*)(xbuf + base + c0 + 4) = make_float4(o[4], o[5], o[6], o[7]);
    *(uint4*)(xbf + base + c0) = pk;
    if (out) {
        float fr = frac[t];
        *(float4*)(out + base + c0)     = make_float4(o[0]*fr, o[1]*fr, o[2]*fr, o[3]*fr);
        *(float4*)(out + base + c0 + 4) = make_float4(o[4]*fr, o[5]*fr, o[6]*fr, o[7]*fr);
    }
}

extern "C" void kernel_launch(void* const* d_in, const int* in_sizes, int n_in,
                              void* d_out, int out_size, void* d_ws, size_t ws_size,
                              hipStream_t stream) {
    const int*   Z      = (const int*)d_in[0];
    const float* frac   = (const float*)d_in[1];
    const float* emb0   = (const float*)d_in[2];
    const float* p0w    = (const float*)d_in[3];
    const float* p0b    = (const float*)d_in[4];
    const float* emb1   = (const float*)d_in[5];
    const float* p1w    = (const float*)d_in[6];
    const float* p1b    = (const float*)d_in[7];
    const float* emb2   = (const float*)d_in[8];
    const float* p2w    = (const float*)d_in[9];
    const float* p2b    = (const float*)d_in[10];
    const float* keys   = (const float*)d_in[11];
    const float* rw     = (const float*)d_in[12];
    const float* rb     = (const float*)d_in[13];
    const float* ew1    = (const float*)d_in[14];
    const float* eb1    = (const float*)d_in[15];
    const float* ew2    = (const float*)d_in[16];
    const float* eb2    = (const float*)d_in[17];
    const float* qkv_w  = (const float*)d_in[18];
    const float* qkv_b  = (const float*)d_in[19];
    const float* aow    = (const float*)d_in[20];
    const float* aob    = (const float*)d_in[21];
    const float* ln1g   = (const float*)d_in[22];
    const float* ln1b   = (const float*)d_in[23];
    const float* ln2g   = (const float*)d_in[24];
    const float* ln2b   = (const float*)d_in[25];
    const float* fw1    = (const float*)d_in[26];
    const float* fb1    = (const float*)d_in[27];
    const float* fw2    = (const float*)d_in[28];
    const float* fb2    = (const float*)d_in[29];
    float* out = (float*)d_out;

    // workspace layout (~121 MB, no aliasing)
    char* p = (char*)d_ws;
    ushort_t* vbf  = (ushort_t*)p;      p += 864 * 512 * 2;
    ushort_t* h    = (ushort_t*)p;      p += 3456 * 2048 * 2;
    float* yall    = (float*)p;         p += 2 * 3456 * 512 * 4;
    ushort_t* qkvwt= (ushort_t*)p;      p += 3 * 1536 * 512 * 2;
    ushort_t* aowt = (ushort_t*)p;      p += 3 * 512 * 512 * 2;
    ushort_t* fw1t = (ushort_t*)p;      p += 3 * 2048 * 512 * 2;
    ushort_t* fw2t = (ushort_t*)p;      p += 3 * 512 * 2048 * 2;
    ushort_t* ew1t = (ushort_t*)p;      p += (size_t)NEXP * 2048 * 512 * 2;
    ushort_t* ew2t = (ushort_t*)p;      p += (size_t)NEXP * 512 * 2048 * 2;
    float* xbuf = (float*)p;            p += 288 * 512 * 4;
    ushort_t* xbf = (ushort_t*)p;       p += 288 * 512 * 2;
    ushort_t* qkvb = (ushort_t*)p;      p += 288 * 1536 * 2;
    float* tmp  = (float*)p;            p += 4 * 288 * 512 * 4;
    ushort_t* f1b = (ushort_t*)p;       p += 288 * 2048 * 2;
    float* w4   = (float*)p;            p += 3456 * 4;
    int* idx4   = (int*)p;              p += 3456 * 4;
    int* offs   = (int*)p;              p += 256;
    int* rows_tv= (int*)p;              p += 3456 * 4;
    int* rows_s = (int*)p;              p += 3456 * 4;
    int* seg_e  = (int*)p;              p += 128 * 4;
    int* seg_r0 = (int*)p;              p += 128 * 4;
    int* nseg   = (int*)p;              p += 256;

    // front: 864 token blocks FIRST + 8192 MoE-weight transpose tail (round-2 structure)
    front_kernel<<<dim3(NTV + 8192), dim3(256), 0, stream>>>(
        Z, emb0, p0w, p0b, emb1, p1w, p1b, emb2, p2w, p2b,
        keys, rw, rb, vbf, w4, idx4, ew1, ew2, ew1t, ew2t);
    route_kernel<<<dim3(1), dim3(256), 0, stream>>>(idx4, offs, rows_tv, rows_s,
                                                    seg_e, seg_r0, nseg);
    moe_gemm1<<<dim3(HFF / 64, MAXSEG), dim3(256), 0, stream>>>(
        vbf, rows_tv, offs, seg_e, seg_r0, nseg, ew1t, eb1, h);
    moe_gemm2<<<dim3(DMODEL / 64, MAXSEG, 2), dim3(256), 0, stream>>>(
        h, rows_s, offs, seg_e, seg_r0, nseg, ew2t, eb2, yall);
    fuse_kernel<<<dim3(NTOK + 1536), dim3(256), 0, stream>>>(
        yall, w4, frac, xbuf, xbf, qkv_w, aow, fw1, qkvwt, aowt, fw1t);

    for (int i = 0; i < 3; ++i) {
        qkv_kernel<<<dim3(i == 0 ? 24 + 154 : 24, 5), dim3(256), 0, stream>>>(
            xbf, qkvwt + (size_t)i * 1536 * 512, qkv_b + i * 1536, qkvb, fw2, fw2t);
        attn_block<<<dim3(32), dim3(256), 0, stream>>>(
            qkvb, aowt + (size_t)i * 512 * 512, aob + i * 512,
            xbuf, xbf, ln1g + i * 512, ln1b + i * 512);
        ffn1_kernel<<<dim3(32, 5), dim3(256), 0, stream>>>(
            xbf, fw1t + (size_t)i * 2048 * 512, fb1 + i * 2048, f1b);
        ffn2_kernel<<<dim3(8, 5, 4), dim3(256), 0, stream>>>(
            f1b, fw2t + (size_t)i * 512 * 2048, fb2 + i * 512, tmp);
        ln2_kernel<<<dim3(72), dim3(256), 0, stream>>>(
            xbuf, xbf, tmp, ln2g + i * 512, ln2b + i * 512,
            (i == 2) ? out : nullptr, frac);
    }
}